// Round 4
// baseline (289.540 us; speedup 1.0000x reference)
//
#include <hip/hip_runtime.h>
#include <hip/hip_bf16.h>
#include <hip/hip_fp16.h>

#define N_NODES 10000
#define N_EDGES 640000
#define TOT_E   (N_EDGES + N_NODES)
#define HID     128
#define NEG_SLOPE 0.2f
#define N_ACT   4096

// ---- bucket counting-sort CSR build ----
#define NBKT   250
#define NPB    40                        // nodes per bucket (250*40 = 10000 exactly)
#define CAP    4096                      // per-bucket capacity (mean ~2600, +25σ margin)
#define P1_EPB 4096
#define P1_EPT 16
#define P1_BLOCKS ((TOT_E + P1_EPB - 1) / P1_EPB)

__global__ void zero_bcur_k(int* __restrict__ bcur) {
    if (threadIdx.x < NBKT) bcur[threadIdx.x] = 0;
}

// Pass 1: partition edges into 250 dst-range buckets, packed (dst<<16)|src.
__global__ __launch_bounds__(256) void part1_k(const int* __restrict__ ei,
                                               unsigned* __restrict__ bpart,
                                               int* __restrict__ bcur) {
    __shared__ int hist[256];
    __shared__ int lofs[256];
    __shared__ int gbase[256];
    __shared__ int sc[256];
    __shared__ unsigned stage[P1_EPB];
    __shared__ unsigned char bkt_of[P1_EPB];
    int t = threadIdx.x;
    hist[t] = 0;
    __syncthreads();

    unsigned pk[P1_EPT];
    int bk[P1_EPT];
    int e0 = blockIdx.x * P1_EPB;
#pragma unroll
    for (int i = 0; i < P1_EPT; i++) {
        int e = e0 + i * 256 + t;
        if (e < TOT_E) {
            int src, dst;
            if (e < N_EDGES) { src = ei[e]; dst = ei[N_EDGES + e]; }
            else             { src = e - N_EDGES; dst = src; }
            pk[i] = ((unsigned)dst << 16) | (unsigned)src;
            bk[i] = dst / NPB;
            atomicAdd(&hist[bk[i]], 1);
        } else bk[i] = -1;
    }
    __syncthreads();
    // block-wide exclusive scan of hist[256]
    int v = hist[t];
    sc[t] = v;
    __syncthreads();
    for (int o = 1; o < 256; o <<= 1) {
        int u = (t >= o) ? sc[t - o] : 0;
        __syncthreads();
        sc[t] += u;
        __syncthreads();
    }
    lofs[t] = sc[t] - v;
    if (v > 0 || t < NBKT) gbase[t] = atomicAdd(&bcur[t], v);
    hist[t] = 0;
    __syncthreads();
#pragma unroll
    for (int i = 0; i < P1_EPT; i++) {
        if (bk[i] >= 0) {
            int p = atomicAdd(&hist[bk[i]], 1);
            int slot = lofs[bk[i]] + p;
            stage[slot] = pk[i];
            bkt_of[slot] = (unsigned char)bk[i];
        }
    }
    __syncthreads();
    int nv = min(P1_EPB, TOT_E - e0);
    for (int s = t; s < nv; s += 256) {
        int b = bkt_of[s];
        bpart[b * CAP + gbase[b] + (s - lofs[b])] = stage[s];
    }
}

// Pass 2: one block per bucket (250 blocks) -> node histogram, offs[], scatter csr.
__global__ __launch_bounds__(256) void part2_k(const unsigned* __restrict__ bpart,
                                               const int* __restrict__ bcur,
                                               int* __restrict__ csr,
                                               int* __restrict__ offs) {
    __shared__ int nhist[NPB];
    __shared__ int sc[256];
    __shared__ int bstart_s;
    int b = blockIdx.x, t = threadIdx.x;
    // block-wide scan of bcur[250] -> bucket start
    int v = (t < NBKT) ? bcur[t] : 0;
    sc[t] = v;
    __syncthreads();
    for (int o = 1; o < 256; o <<= 1) {
        int u = (t >= o) ? sc[t - o] : 0;
        __syncthreads();
        sc[t] += u;
        __syncthreads();
    }
    if (t == b) bstart_s = sc[t] - v;
    if (b == 0 && t == 255) offs[N_NODES] = sc[255];
    if (t < NPB) nhist[t] = 0;
    __syncthreads();

    int cnt = bcur[b];
    int n0 = b * NPB;
    const unsigned* bp = bpart + b * CAP;

    for (int i = t; i < cnt; i += 256) {
        int dst = bp[i] >> 16;
        atomicAdd(&nhist[dst - n0], 1);
    }
    __syncthreads();
    if (t < 64) {
        int v2 = (t < NPB) ? nhist[t] : 0;
        int s2 = v2;
        for (int o = 1; o < 64; o <<= 1) {
            int u = __shfl_up(s2, o, 64);
            if (t >= o) s2 += u;
        }
        if (t < NPB) {
            int ofs = bstart_s + s2 - v2;
            nhist[t] = ofs;
            offs[n0 + t] = ofs;
        }
    }
    __syncthreads();
    for (int i = t; i < cnt; i += 256) {
        unsigned pk = bp[i];
        int dst = pk >> 16, src = pk & 0xFFFF;
        int p = atomicAdd(&nhist[dst - n0], 1);
        csr[p] = src;
    }
}

// -------- gemm + fused attention dots: z16 = fp16(h@W), zs = z@a_src, zd = z@a_dst --------

__global__ __launch_bounds__(256) void gemm_k(const float* __restrict__ A,
                                              const float* __restrict__ W,
                                              const float* __restrict__ avs,
                                              const float* __restrict__ avd,
                                              __half* __restrict__ z16,
                                              float* __restrict__ zs,
                                              float* __restrict__ zd) {
    __shared__ float Wl[HID * HID];
    int t = threadIdx.x;
    {
        const float4* W4 = (const float4*)W;
        float4* Wl4 = (float4*)Wl;
        for (int i = t; i < HID * HID / 4; i += 256) Wl4[i] = W4[i];
    }
    __syncthreads();
    int tx = t & 31;
    int ty = t >> 5;
    int row0 = blockIdx.x * 32 + ty * 4;
    float acc[4][4] = {{0.f}};
    for (int k = 0; k < HID; k += 4) {
        float ar[4][4];
#pragma unroll
        for (int r = 0; r < 4; r++) {
            int row = row0 + r;
            float4 av = (row < N_NODES) ? *(const float4*)&A[row * HID + k]
                                        : make_float4(0.f, 0.f, 0.f, 0.f);
            ar[r][0] = av.x; ar[r][1] = av.y; ar[r][2] = av.z; ar[r][3] = av.w;
        }
#pragma unroll
        for (int kk = 0; kk < 4; kk++) {
            float4 wv = *(const float4*)&Wl[(k + kk) * HID + tx * 4];
#pragma unroll
            for (int r = 0; r < 4; r++) {
                acc[r][0] = fmaf(ar[r][kk], wv.x, acc[r][0]);
                acc[r][1] = fmaf(ar[r][kk], wv.y, acc[r][1]);
                acc[r][2] = fmaf(ar[r][kk], wv.z, acc[r][2]);
                acc[r][3] = fmaf(ar[r][kk], wv.w, acc[r][3]);
            }
        }
    }
    float4 asv = *(const float4*)&avs[tx * 4];
    float4 adv = *(const float4*)&avd[tx * 4];
#pragma unroll
    for (int r = 0; r < 4; r++) {
        int row = row0 + r;
        if (row < N_NODES) {
            *(__half2*)&z16[row * HID + tx * 4]     = __floats2half2_rn(acc[r][0], acc[r][1]);
            *(__half2*)&z16[row * HID + tx * 4 + 2] = __floats2half2_rn(acc[r][2], acc[r][3]);
        }
        float ps = acc[r][0] * asv.x + acc[r][1] * asv.y + acc[r][2] * asv.z + acc[r][3] * asv.w;
        float pd = acc[r][0] * adv.x + acc[r][1] * adv.y + acc[r][2] * adv.z + acc[r][3] * adv.w;
#pragma unroll
        for (int o = 1; o < 32; o <<= 1) {
            ps += __shfl_xor(ps, o, 64);
            pd += __shfl_xor(pd, o, 64);
        }
        if (tx == 0 && row < N_NODES) { zs[row] = ps; zd[row] = pd; }
    }
}

// -------- edge-softmax + aggregate: 1 wave/node, register stage + readlane broadcast --------

__global__ __launch_bounds__(256) void agg_k(const __half* __restrict__ z16,
                                             const float* __restrict__ zs,
                                             const float* __restrict__ zd,
                                             const int* __restrict__ offs,
                                             const int* __restrict__ csr,
                                             const float* __restrict__ b,
                                             float* __restrict__ hout) {
    int t = threadIdx.x;
    int w = t >> 6, lane = t & 63;
    int n = blockIdx.x * 4 + w;
    if (n >= N_NODES) return;
    int o0 = offs[n];
    int deg = offs[n + 1] - o0;
    float zdn = zd[n];
    const __half2* z2 = (const __half2*)z16 + lane;
    float accx = 0.f, accy = 0.f, denom = 0.f;

    for (int base = 0; base < deg; base += 64) {
        int j = base + lane;
        int sreg = 0;
        float ex = 0.f;
        if (j < deg) {
            int s = csr[o0 + j];
            sreg = s;
            float e = zs[s] + zdn;
            e = e > 0.f ? e : NEG_SLOPE * e;
            ex = __expf(e);                      // no max-shift: logits bounded
        }
        int cnt = min(64, deg - base);
        int q = 0;
        for (; q + 8 <= cnt; q += 8) {
#pragma unroll
            for (int u = 0; u < 8; u++) {
                int sq = __builtin_amdgcn_readlane(sreg, q + u);
                float exq = __uint_as_float(
                    __builtin_amdgcn_readlane(__float_as_uint(ex), q + u));
                denom += exq;
                float2 vf = __half22float2(z2[sq * 64]);
                accx = fmaf(exq, vf.x, accx);
                accy = fmaf(exq, vf.y, accy);
            }
        }
        for (; q < cnt; q++) {
            int sq = __builtin_amdgcn_readlane(sreg, q);
            float exq = __uint_as_float(
                __builtin_amdgcn_readlane(__float_as_uint(ex), q));
            denom += exq;
            float2 vf = __half22float2(z2[sq * 64]);
            accx = fmaf(exq, vf.x, accx);
            accy = fmaf(exq, vf.y, accy);
        }
    }
    float inv = 1.0f / denom;
    float2 bv = *(const float2*)&b[2 * lane];
    float vx = accx * inv + bv.x;
    float vy = accy * inv + bv.y;
    float2 o;
    o.x = vx > 0.f ? vx : 0.f;
    o.y = vy > 0.f ? vy : 0.f;
    *(float2*)&hout[n * HID + 2 * lane] = o;
}

// -------- action scoring MLP: 16 actions/block, W1 streamed once per block --------

#define ACT_PB 16

__global__ __launch_bounds__(256) void score_k(const float* __restrict__ h,
                                               const int* __restrict__ asrc,
                                               const int* __restrict__ adst,
                                               const int* __restrict__ atype,
                                               const float* __restrict__ W1,
                                               const float* __restrict__ b1,
                                               const float* __restrict__ W2,
                                               const float* __restrict__ b2,
                                               float* __restrict__ out) {
    __shared__ float feat[ACT_PB][264];     // 257 used, padded
    int t = threadIdx.x;
    int a0 = blockIdx.x * ACT_PB;
    for (int idx = t; idx < ACT_PB * 256; idx += 256) {
        int a = idx >> 8, c = idx & 255;
        int node = (c < 128) ? asrc[a0 + a] : adst[a0 + a];
        feat[a][c] = h[node * HID + (c & 127)];
    }
    if (t < ACT_PB) feat[t][256] = (float)atype[a0 + t];
    __syncthreads();

    int cg = t & 15;                        // 8 cols each: cg*8
    int ar = t >> 4;                        // action 0..15
    float acc[8];
    {
        float4 ba = *(const float4*)&b1[cg * 8];
        float4 bb = *(const float4*)&b1[cg * 8 + 4];
        acc[0] = ba.x; acc[1] = ba.y; acc[2] = ba.z; acc[3] = ba.w;
        acc[4] = bb.x; acc[5] = bb.y; acc[6] = bb.z; acc[7] = bb.w;
    }
    const float* fa = feat[ar];
#pragma unroll 4
    for (int k = 0; k < 257; k++) {
        float f = fa[k];
        float4 w0 = *(const float4*)&W1[k * HID + cg * 8];
        float4 w1 = *(const float4*)&W1[k * HID + cg * 8 + 4];
        acc[0] = fmaf(f, w0.x, acc[0]);
        acc[1] = fmaf(f, w0.y, acc[1]);
        acc[2] = fmaf(f, w0.z, acc[2]);
        acc[3] = fmaf(f, w0.w, acc[3]);
        acc[4] = fmaf(f, w1.x, acc[4]);
        acc[5] = fmaf(f, w1.y, acc[5]);
        acc[6] = fmaf(f, w1.z, acc[6]);
        acc[7] = fmaf(f, w1.w, acc[7]);
    }
    float4 w2a = *(const float4*)&W2[cg * 8];
    float4 w2b = *(const float4*)&W2[cg * 8 + 4];
    float v = 0.f;
    v += (acc[0] > 0.f ? acc[0] : 0.f) * w2a.x;
    v += (acc[1] > 0.f ? acc[1] : 0.f) * w2a.y;
    v += (acc[2] > 0.f ? acc[2] : 0.f) * w2a.z;
    v += (acc[3] > 0.f ? acc[3] : 0.f) * w2a.w;
    v += (acc[4] > 0.f ? acc[4] : 0.f) * w2b.x;
    v += (acc[5] > 0.f ? acc[5] : 0.f) * w2b.y;
    v += (acc[6] > 0.f ? acc[6] : 0.f) * w2b.z;
    v += (acc[7] > 0.f ? acc[7] : 0.f) * w2b.w;
#pragma unroll
    for (int o = 1; o < 16; o <<= 1) v += __shfl_xor(v, o, 64);
    if (cg == 0) out[a0 + ar] = v + b2[0];
}

// ---------------- launch ----------------

extern "C" void kernel_launch(void* const* d_in, const int* in_sizes, int n_in,
                              void* d_out, int out_size, void* d_ws, size_t ws_size,
                              hipStream_t stream) {
    const float* x   = (const float*)d_in[0];
    const int* ei    = (const int*)d_in[1];
    const int* asrc  = (const int*)d_in[2];
    const int* adst  = (const int*)d_in[3];
    const int* atype = (const int*)d_in[4];
    const float* gW  = (const float*)d_in[5];
    const float* gas = (const float*)d_in[6];
    const float* gad = (const float*)d_in[7];
    const float* gb  = (const float*)d_in[8];
    const float* W1  = (const float*)d_in[9];
    const float* b1  = (const float*)d_in[10];
    const float* W2  = (const float*)d_in[11];
    const float* b2  = (const float*)d_in[12];
    float* out = (float*)d_out;

    __half* z16 = (__half*)d_ws;                    // 2.56 MB
    float* hA = (float*)(z16 + N_NODES * HID);      // 5.12 MB
    float* hB = hA + N_NODES * HID;                 // 5.12 MB
    float* zs = hB + N_NODES * HID;
    float* zd = zs + N_NODES;
    int* offs = (int*)(zd + N_NODES);
    int* csr  = offs + (N_NODES + 1);
    int* bcur = csr + TOT_E;
    unsigned* bpart = (unsigned*)d_ws;              // 250*4096*4 = 4.1 MB, aliases z16/hA head

    zero_bcur_k<<<1, 256, 0, stream>>>(bcur);
    part1_k<<<P1_BLOCKS, 256, 0, stream>>>(ei, bpart, bcur);
    part2_k<<<NBKT, 256, 0, stream>>>(bpart, bcur, csr, offs);

    const float* hin = x;
    float* bufs[3] = { hA, hB, hA };
    for (int l = 0; l < 3; l++) {
        gemm_k<<<(N_NODES + 31) / 32, 256, 0, stream>>>(hin, gW + l * HID * HID,
                                                        gas + l * HID, gad + l * HID,
                                                        z16, zs, zd);
        agg_k<<<(N_NODES + 3) / 4, 256, 0, stream>>>(z16, zs, zd, offs, csr,
                                                     gb + l * HID, bufs[l]);
        hin = bufs[l];
    }
    score_k<<<N_ACT / ACT_PB, 256, 0, stream>>>(hin, asrc, adst, atype,
                                                W1, b1, W2, b2, out);
}

// Round 5
// 281.357 us; speedup vs baseline: 1.0291x; 1.0291x over previous
//
#include <hip/hip_runtime.h>
#include <hip/hip_bf16.h>
#include <hip/hip_fp16.h>

#define N_NODES 10000
#define N_EDGES 640000
#define TOT_E   (N_EDGES + N_NODES)
#define HID     128
#define NEG_SLOPE 0.2f
#define N_ACT   4096

// ---- deterministic bucket counting-sort CSR build (no global atomics) ----
#define NBKT   250
#define NPB    40                        // 250*40 = 10000 exactly
#define P1_EPB 4096
#define P1_EPT 16
#define P1_BLOCKS 159                    // ceil(650000/4096)
#define SLOTP  56                        // max edges per (block,bucket); mean 16.4, ~10 sigma margin

// Pass 1: per-block bucket sort; run for (blk,bucket) stored at fixed slot, counts to bcnt.
__global__ __launch_bounds__(256) void part1_k(const int* __restrict__ ei,
                                               unsigned* __restrict__ bpart,
                                               int* __restrict__ bcnt) {
    __shared__ int hist[256];
    __shared__ int lofs[256];
    __shared__ int sc[256];
    __shared__ unsigned stage[P1_EPB];
    __shared__ unsigned char bkt_of[P1_EPB];
    int t = threadIdx.x;
    hist[t] = 0;
    __syncthreads();

    unsigned pk[P1_EPT];
    int bk[P1_EPT];
    int e0 = blockIdx.x * P1_EPB;
#pragma unroll
    for (int i = 0; i < P1_EPT; i++) {
        int e = e0 + i * 256 + t;
        if (e < TOT_E) {
            int src, dst;
            if (e < N_EDGES) { src = ei[e]; dst = ei[N_EDGES + e]; }
            else             { src = e - N_EDGES; dst = src; }
            pk[i] = ((unsigned)dst << 16) | (unsigned)src;
            bk[i] = dst / NPB;
            atomicAdd(&hist[bk[i]], 1);
        } else bk[i] = -1;
    }
    __syncthreads();
    int v = hist[t];
    sc[t] = v;
    __syncthreads();
    for (int o = 1; o < 256; o <<= 1) {
        int u = (t >= o) ? sc[t - o] : 0;
        __syncthreads();
        sc[t] += u;
        __syncthreads();
    }
    lofs[t] = sc[t] - v;
    bcnt[blockIdx.x * 256 + t] = v;      // counts (t>=NBKT are 0)
    hist[t] = 0;
    __syncthreads();
#pragma unroll
    for (int i = 0; i < P1_EPT; i++) {
        if (bk[i] >= 0) {
            int p = atomicAdd(&hist[bk[i]], 1);   // LDS atomic only
            int slot = lofs[bk[i]] + p;
            stage[slot] = pk[i];
            bkt_of[slot] = (unsigned char)bk[i];
        }
    }
    __syncthreads();
    int nv = min(P1_EPB, TOT_E - e0);
    for (int s = t; s < nv; s += 256) {
        int b = bkt_of[s];
        bpart[b * (P1_BLOCKS * SLOTP) + blockIdx.x * SLOTP + (s - lofs[b])] = stage[s];
    }
}

// Pass 2: one block per bucket: compact 159 runs to LDS, node histogram, offs[], csr scatter.
__global__ __launch_bounds__(256) void part2_k(const unsigned* __restrict__ bpart,
                                               const int* __restrict__ bcnt,
                                               int* __restrict__ csr,
                                               int* __restrict__ offs) {
    __shared__ unsigned ebuf[4096];
    __shared__ int sc[256];
    __shared__ int nhist[NPB];
    __shared__ int bstart_s, cnt_s;
    int b = blockIdx.x, t = threadIdx.x;

    // bucket totals (each thread sums one bucket's column) -> scan -> this bucket's csr start
    int tot = 0;
    if (t < NBKT)
        for (int blk = 0; blk < P1_BLOCKS; blk++) tot += bcnt[blk * 256 + t];
    sc[t] = (t < NBKT) ? tot : 0;
    __syncthreads();
    for (int o = 1; o < 256; o <<= 1) {
        int u = (t >= o) ? sc[t - o] : 0;
        __syncthreads();
        sc[t] += u;
        __syncthreads();
    }
    if (t == b) { bstart_s = sc[t] - tot; cnt_s = tot; }
    if (b == 0 && t == 255) offs[N_NODES] = sc[255];
    __syncthreads();

    // run prefix within bucket, compact runs into ebuf
    int L = (t < P1_BLOCKS) ? bcnt[t * 256 + b] : 0;
    sc[t] = L;
    __syncthreads();
    for (int o = 1; o < 256; o <<= 1) {
        int u = (t >= o) ? sc[t - o] : 0;
        __syncthreads();
        sc[t] += u;
        __syncthreads();
    }
    int P = sc[t] - L;
    if (t < NPB) nhist[t] = 0;
    if (t < P1_BLOCKS && L > 0) {
        const unsigned* myrun = bpart + b * (P1_BLOCKS * SLOTP) + t * SLOTP;
        for (int i = 0; i < L; i++) ebuf[P + i] = myrun[i];
    }
    __syncthreads();

    int cnt = cnt_s;
    int n0 = b * NPB;
    for (int i = t; i < cnt; i += 256) atomicAdd(&nhist[(ebuf[i] >> 16) - n0], 1);
    __syncthreads();
    if (t < 64) {
        int v2 = (t < NPB) ? nhist[t] : 0;
        int s2 = v2;
        for (int o = 1; o < 64; o <<= 1) {
            int u = __shfl_up(s2, o, 64);
            if (t >= o) s2 += u;
        }
        if (t < NPB) {
            int ofs = bstart_s + s2 - v2;
            nhist[t] = ofs;
            offs[n0 + t] = ofs;
        }
    }
    __syncthreads();
    for (int i = t; i < cnt; i += 256) {
        unsigned pk = ebuf[i];
        int p = atomicAdd(&nhist[(pk >> 16) - n0], 1);
        csr[p] = pk & 0xFFFF;
    }
}

// -------- per-wave edge aggregate core (readlane broadcast) --------
__device__ __forceinline__ void agg_node(const __half2* __restrict__ z2,   // pre-offset by lane
                                         const float* __restrict__ zsi, float zdn,
                                         const int* __restrict__ csr, int o0, int deg,
                                         int lane, float& accx, float& accy, float& denom) {
    for (int base = 0; base < deg; base += 64) {
        int j = base + lane;
        int sreg = 0;
        float ex = 0.f;
        if (j < deg) {
            int s = csr[o0 + j];
            sreg = s;
            float e = zsi[s] + zdn;
            e = e > 0.f ? e : NEG_SLOPE * e;
            ex = __expf(e);                      // no max-shift: logits bounded
        }
        int cnt = min(64, deg - base);
        int q = 0;
        for (; q + 8 <= cnt; q += 8) {
#pragma unroll
            for (int u = 0; u < 8; u++) {
                int sq = __builtin_amdgcn_readlane(sreg, q + u);
                float exq = __uint_as_float(
                    __builtin_amdgcn_readlane(__float_as_uint(ex), q + u));
                denom += exq;
                float2 vf = __half22float2(z2[sq * 64]);
                accx = fmaf(exq, vf.x, accx);
                accy = fmaf(exq, vf.y, accy);
            }
        }
        for (; q < cnt; q++) {
            int sq = __builtin_amdgcn_readlane(sreg, q);
            float exq = __uint_as_float(
                __builtin_amdgcn_readlane(__float_as_uint(ex), q));
            denom += exq;
            float2 vf = __half22float2(z2[sq * 64]);
            accx = fmaf(exq, vf.x, accx);
            accy = fmaf(exq, vf.y, accy);
        }
    }
}

// -------- gemm0: z16 = fp16(x@W), zs, zd (layer 0, reads fp32 x) --------

__global__ __launch_bounds__(256) void gemm_k(const float* __restrict__ A,
                                              const float* __restrict__ W,
                                              const float* __restrict__ avs,
                                              const float* __restrict__ avd,
                                              __half* __restrict__ z16,
                                              float* __restrict__ zs,
                                              float* __restrict__ zd) {
    __shared__ float Wl[HID * HID];
    int t = threadIdx.x;
    {
        const float4* W4 = (const float4*)W;
        float4* Wl4 = (float4*)Wl;
        for (int i = t; i < HID * HID / 4; i += 256) Wl4[i] = W4[i];
    }
    __syncthreads();
    int tx = t & 31;
    int ty = t >> 5;
    int row0 = blockIdx.x * 32 + ty * 4;
    float acc[4][4] = {{0.f}};
    for (int k = 0; k < HID; k += 4) {
        float ar[4][4];
#pragma unroll
        for (int r = 0; r < 4; r++) {
            int row = row0 + r;
            float4 av = (row < N_NODES) ? *(const float4*)&A[row * HID + k]
                                        : make_float4(0.f, 0.f, 0.f, 0.f);
            ar[r][0] = av.x; ar[r][1] = av.y; ar[r][2] = av.z; ar[r][3] = av.w;
        }
#pragma unroll
        for (int kk = 0; kk < 4; kk++) {
            float4 wv = *(const float4*)&Wl[(k + kk) * HID + tx * 4];
#pragma unroll
            for (int r = 0; r < 4; r++) {
                acc[r][0] = fmaf(ar[r][kk], wv.x, acc[r][0]);
                acc[r][1] = fmaf(ar[r][kk], wv.y, acc[r][1]);
                acc[r][2] = fmaf(ar[r][kk], wv.z, acc[r][2]);
                acc[r][3] = fmaf(ar[r][kk], wv.w, acc[r][3]);
            }
        }
    }
    float4 asv = *(const float4*)&avs[tx * 4];
    float4 adv = *(const float4*)&avd[tx * 4];
#pragma unroll
    for (int r = 0; r < 4; r++) {
        int row = row0 + r;
        if (row < N_NODES) {
            *(__half2*)&z16[row * HID + tx * 4]     = __floats2half2_rn(acc[r][0], acc[r][1]);
            *(__half2*)&z16[row * HID + tx * 4 + 2] = __floats2half2_rn(acc[r][2], acc[r][3]);
        }
        float ps = acc[r][0] * asv.x + acc[r][1] * asv.y + acc[r][2] * asv.z + acc[r][3] * asv.w;
        float pd = acc[r][0] * adv.x + acc[r][1] * adv.y + acc[r][2] * adv.z + acc[r][3] * adv.w;
#pragma unroll
        for (int o = 1; o < 32; o <<= 1) {
            ps += __shfl_xor(ps, o, 64);
            pd += __shfl_xor(pd, o, 64);
        }
        if (tx == 0 && row < N_NODES) { zs[row] = ps; zd[row] = pd; }
    }
}

// -------- fused: agg(layer l) -> h-tile in LDS -> gemm(layer l+1) -> z16/zs/zd --------
// 16 nodes/block, 256 threads. h never touches global memory.

__global__ __launch_bounds__(256) void fuse_k(const __half* __restrict__ z16i,
                                              const float* __restrict__ zsi,
                                              const float* __restrict__ zdi,
                                              const int* __restrict__ offs,
                                              const int* __restrict__ csr,
                                              const float* __restrict__ bprev,
                                              const float* __restrict__ W,
                                              const float* __restrict__ avs,
                                              const float* __restrict__ avd,
                                              __half* __restrict__ z16o,
                                              float* __restrict__ zso,
                                              float* __restrict__ zdo) {
    __shared__ float hT[16][HID];        // 8 KB
    __shared__ float Wc[32 * HID];       // 16 KB chunk of W
    int t = threadIdx.x;
    int w = t >> 6, lane = t & 63;
    int n0 = blockIdx.x * 16;
    const __half2* z2 = (const __half2*)z16i + lane;

    // ---- agg phase: wave w handles local nodes 4w..4w+3 ----
    float2 bv = *(const float2*)&bprev[2 * lane];
#pragma unroll
    for (int i = 0; i < 4; i++) {
        int ln = w * 4 + i;
        int n = n0 + ln;
        int o0 = offs[n];
        int deg = offs[n + 1] - o0;
        float zdn = zdi[n];
        float accx = 0.f, accy = 0.f, denom = 0.f;
        agg_node(z2, zsi, zdn, csr, o0, deg, lane, accx, accy, denom);
        float inv = 1.0f / denom;
        float vx = accx * inv + bv.x;
        float vy = accy * inv + bv.y;
        float2 hv;
        hv.x = vx > 0.f ? vx : 0.f;
        hv.y = vy > 0.f ? vy : 0.f;
        *(float2*)&hT[ln][2 * lane] = hv;
    }
    __syncthreads();

    // ---- gemm phase: 16 x 128 = (16 x 128) @ (128 x 128), W in 4 LDS chunks ----
    int tx = t & 31, ty = t >> 5;
    int r0 = ty * 2, r1 = ty * 2 + 1;
    float acc[2][4] = {{0.f}};
    for (int c = 0; c < 4; c++) {
        if (c) __syncthreads();
        {
            const float4* W4 = (const float4*)(W + c * 32 * HID);
            float4* Wc4 = (float4*)Wc;
#pragma unroll
            for (int i = 0; i < 4; i++) Wc4[t + 256 * i] = W4[t + 256 * i];
        }
        __syncthreads();
#pragma unroll
        for (int kk = 0; kk < 32; kk += 4) {
            float a0v[4], a1v[4];
            *(float4*)a0v = *(const float4*)&hT[r0][c * 32 + kk];
            *(float4*)a1v = *(const float4*)&hT[r1][c * 32 + kk];
#pragma unroll
            for (int u = 0; u < 4; u++) {
                float4 wv = *(const float4*)&Wc[(kk + u) * HID + tx * 4];
                acc[0][0] = fmaf(a0v[u], wv.x, acc[0][0]);
                acc[0][1] = fmaf(a0v[u], wv.y, acc[0][1]);
                acc[0][2] = fmaf(a0v[u], wv.z, acc[0][2]);
                acc[0][3] = fmaf(a0v[u], wv.w, acc[0][3]);
                acc[1][0] = fmaf(a1v[u], wv.x, acc[1][0]);
                acc[1][1] = fmaf(a1v[u], wv.y, acc[1][1]);
                acc[1][2] = fmaf(a1v[u], wv.z, acc[1][2]);
                acc[1][3] = fmaf(a1v[u], wv.w, acc[1][3]);
            }
        }
    }
    // epilogue: z16 store + dots
    float4 asv = *(const float4*)&avs[tx * 4];
    float4 adv = *(const float4*)&avd[tx * 4];
#pragma unroll
    for (int r = 0; r < 2; r++) {
        int row = n0 + (r ? r1 : r0);
        *(__half2*)&z16o[row * HID + tx * 4]     = __floats2half2_rn(acc[r][0], acc[r][1]);
        *(__half2*)&z16o[row * HID + tx * 4 + 2] = __floats2half2_rn(acc[r][2], acc[r][3]);
        float ps = acc[r][0] * asv.x + acc[r][1] * asv.y + acc[r][2] * asv.z + acc[r][3] * asv.w;
        float pd = acc[r][0] * adv.x + acc[r][1] * adv.y + acc[r][2] * adv.z + acc[r][3] * adv.w;
#pragma unroll
        for (int o = 1; o < 32; o <<= 1) {
            ps += __shfl_xor(ps, o, 64);
            pd += __shfl_xor(pd, o, 64);
        }
        if (tx == 0) { zso[row] = ps; zdo[row] = pd; }
    }
}

// -------- final-layer aggregate -> h3 (global) --------

__global__ __launch_bounds__(256) void agg_k(const __half* __restrict__ z16,
                                             const float* __restrict__ zs,
                                             const float* __restrict__ zd,
                                             const int* __restrict__ offs,
                                             const int* __restrict__ csr,
                                             const float* __restrict__ b,
                                             float* __restrict__ hout) {
    int t = threadIdx.x;
    int w = t >> 6, lane = t & 63;
    int n = blockIdx.x * 4 + w;
    if (n >= N_NODES) return;
    int o0 = offs[n];
    int deg = offs[n + 1] - o0;
    float zdn = zd[n];
    const __half2* z2 = (const __half2*)z16 + lane;
    float accx = 0.f, accy = 0.f, denom = 0.f;
    agg_node(z2, zs, zdn, csr, o0, deg, lane, accx, accy, denom);
    float inv = 1.0f / denom;
    float2 bv = *(const float2*)&b[2 * lane];
    float vx = accx * inv + bv.x;
    float vy = accy * inv + bv.y;
    float2 o;
    o.x = vx > 0.f ? vx : 0.f;
    o.y = vy > 0.f ? vy : 0.f;
    *(float2*)&hout[n * HID + 2 * lane] = o;
}

// -------- action scoring MLP: 8 actions/block (512 blocks, 2 blocks/CU) --------

#define ACT_PB 8

__global__ __launch_bounds__(256) void score_k(const float* __restrict__ h,
                                               const int* __restrict__ asrc,
                                               const int* __restrict__ adst,
                                               const int* __restrict__ atype,
                                               const float* __restrict__ W1,
                                               const float* __restrict__ b1,
                                               const float* __restrict__ W2,
                                               const float* __restrict__ b2,
                                               float* __restrict__ out) {
    __shared__ float feat[ACT_PB][264];
    int t = threadIdx.x;
    int a0 = blockIdx.x * ACT_PB;
    for (int idx = t; idx < ACT_PB * 256; idx += 256) {
        int a = idx >> 8, c = idx & 255;
        int node = (c < 128) ? asrc[a0 + a] : adst[a0 + a];
        feat[a][c] = h[node * HID + (c & 127)];
    }
    if (t < ACT_PB) feat[t][256] = (float)atype[a0 + t];
    __syncthreads();

    int cg = t & 31;                        // 4 cols each
    int ar = t >> 5;                        // action 0..7
    float acc0, acc1, acc2, acc3;
    {
        float4 bv = *(const float4*)&b1[cg * 4];
        acc0 = bv.x; acc1 = bv.y; acc2 = bv.z; acc3 = bv.w;
    }
    const float* fa = feat[ar];
#pragma unroll 4
    for (int k = 0; k < 257; k++) {
        float4 wv = *(const float4*)&W1[k * HID + cg * 4];
        float f = fa[k];
        acc0 = fmaf(f, wv.x, acc0);
        acc1 = fmaf(f, wv.y, acc1);
        acc2 = fmaf(f, wv.z, acc2);
        acc3 = fmaf(f, wv.w, acc3);
    }
    acc0 = acc0 > 0.f ? acc0 : 0.f;
    acc1 = acc1 > 0.f ? acc1 : 0.f;
    acc2 = acc2 > 0.f ? acc2 : 0.f;
    acc3 = acc3 > 0.f ? acc3 : 0.f;
    float4 w2v = *(const float4*)&W2[cg * 4];
    float v = acc0 * w2v.x + acc1 * w2v.y + acc2 * w2v.z + acc3 * w2v.w;
#pragma unroll
    for (int o = 1; o < 32; o <<= 1) v += __shfl_xor(v, o, 64);
    if (cg == 0) out[a0 + ar] = v + b2[0];
}

// ---------------- launch ----------------

extern "C" void kernel_launch(void* const* d_in, const int* in_sizes, int n_in,
                              void* d_out, int out_size, void* d_ws, size_t ws_size,
                              hipStream_t stream) {
    const float* x   = (const float*)d_in[0];
    const int* ei    = (const int*)d_in[1];
    const int* asrc  = (const int*)d_in[2];
    const int* adst  = (const int*)d_in[3];
    const int* atype = (const int*)d_in[4];
    const float* gW  = (const float*)d_in[5];
    const float* gas = (const float*)d_in[6];
    const float* gad = (const float*)d_in[7];
    const float* gb  = (const float*)d_in[8];
    const float* W1  = (const float*)d_in[9];
    const float* b1  = (const float*)d_in[10];
    const float* W2  = (const float*)d_in[11];
    const float* b2  = (const float*)d_in[12];
    float* out = (float*)d_out;

    // workspace layout (disjoint, ~22 MB of 268 MB)
    __half* z16A = (__half*)d_ws;                       // 2.56 MB
    __half* z16B = z16A + N_NODES * HID;                // 2.56 MB
    float* h3   = (float*)(z16B + N_NODES * HID);       // 5.12 MB
    float* zsA  = h3 + N_NODES * HID;
    float* zdA  = zsA + N_NODES;
    float* zsB  = zdA + N_NODES;
    float* zdB  = zsB + N_NODES;
    int* offs   = (int*)(zdB + N_NODES);                // 10001
    int* csr    = offs + (N_NODES + 1);                 // 650000
    int* bcnt   = csr + TOT_E;                          // 159*256
    unsigned* bpart = (unsigned*)(bcnt + P1_BLOCKS * 256);  // 250*159*56 u32 (8.9 MB)

    part1_k<<<P1_BLOCKS, 256, 0, stream>>>(ei, bpart, bcnt);
    part2_k<<<NBKT, 256, 0, stream>>>(bpart, bcnt, csr, offs);

    gemm_k<<<(N_NODES + 31) / 32, 256, 0, stream>>>(x, gW, gas, gad, z16A, zsA, zdA);
    fuse_k<<<N_NODES / 16, 256, 0, stream>>>(z16A, zsA, zdA, offs, csr, gb,
                                             gW + 1 * HID * HID, gas + 1 * HID, gad + 1 * HID,
                                             z16B, zsB, zdB);
    fuse_k<<<N_NODES / 16, 256, 0, stream>>>(z16B, zsB, zdB, offs, csr, gb + 1 * HID,
                                             gW + 2 * HID * HID, gas + 2 * HID, gad + 2 * HID,
                                             z16A, zsA, zdA);
    agg_k<<<(N_NODES + 3) / 4, 256, 0, stream>>>(z16A, zsA, zdA, offs, csr,
                                                 gb + 2 * HID, h3);
    score_k<<<N_ACT / ACT_PB, 256, 0, stream>>>(h3, asrc, adst, atype,
                                                W1, b1, W2, b2, out);
}

// Round 6
// 242.726 us; speedup vs baseline: 1.1929x; 1.1592x over previous
//
#include <hip/hip_runtime.h>
#include <hip/hip_bf16.h>
#include <hip/hip_fp16.h>

#define N_NODES 10000
#define N_EDGES 640000
#define TOT_E   (N_EDGES + N_NODES)
#define HID     128
#define NEG_SLOPE 0.2f
#define N_ACT   4096

// ---- deterministic bucket counting-sort CSR build (no global atomics) ----
#define NBKT   250
#define NPB    40
#define P1_EPB 4096
#define P1_EPT 16
#define P1_BLOCKS 159
#define SLOTP  56

__global__ __launch_bounds__(256) void part1_k(const int* __restrict__ ei,
                                               unsigned* __restrict__ bpart,
                                               int* __restrict__ bcnt) {
    __shared__ int hist[256];
    __shared__ int lofs[256];
    __shared__ int sc[256];
    __shared__ unsigned stage[P1_EPB];
    __shared__ unsigned char bkt_of[P1_EPB];
    int t = threadIdx.x;
    hist[t] = 0;
    __syncthreads();

    unsigned pk[P1_EPT];
    int bk[P1_EPT];
    int e0 = blockIdx.x * P1_EPB;
#pragma unroll
    for (int i = 0; i < P1_EPT; i++) {
        int e = e0 + i * 256 + t;
        if (e < TOT_E) {
            int src, dst;
            if (e < N_EDGES) { src = ei[e]; dst = ei[N_EDGES + e]; }
            else             { src = e - N_EDGES; dst = src; }
            pk[i] = ((unsigned)dst << 16) | (unsigned)src;
            bk[i] = dst / NPB;
            atomicAdd(&hist[bk[i]], 1);
        } else bk[i] = -1;
    }
    __syncthreads();
    int v = hist[t];
    sc[t] = v;
    __syncthreads();
    for (int o = 1; o < 256; o <<= 1) {
        int u = (t >= o) ? sc[t - o] : 0;
        __syncthreads();
        sc[t] += u;
        __syncthreads();
    }
    lofs[t] = sc[t] - v;
    bcnt[blockIdx.x * 256 + t] = v;
    hist[t] = 0;
    __syncthreads();
#pragma unroll
    for (int i = 0; i < P1_EPT; i++) {
        if (bk[i] >= 0) {
            int p = atomicAdd(&hist[bk[i]], 1);
            int slot = lofs[bk[i]] + p;
            stage[slot] = pk[i];
            bkt_of[slot] = (unsigned char)bk[i];
        }
    }
    __syncthreads();
    int nv = min(P1_EPB, TOT_E - e0);
    for (int s = t; s < nv; s += 256) {
        int b = bkt_of[s];
        bpart[b * (P1_BLOCKS * SLOTP) + blockIdx.x * SLOTP + (s - lofs[b])] = stage[s];
    }
}

__global__ __launch_bounds__(256) void part2_k(const unsigned* __restrict__ bpart,
                                               const int* __restrict__ bcnt,
                                               int* __restrict__ csr,
                                               int* __restrict__ offs) {
    __shared__ unsigned ebuf[4096];
    __shared__ int sc[256];
    __shared__ int nhist[NPB];
    __shared__ int bstart_s, cnt_s;
    int b = blockIdx.x, t = threadIdx.x;

    int tot = 0;
    if (t < NBKT)
        for (int blk = 0; blk < P1_BLOCKS; blk++) tot += bcnt[blk * 256 + t];
    sc[t] = (t < NBKT) ? tot : 0;
    __syncthreads();
    for (int o = 1; o < 256; o <<= 1) {
        int u = (t >= o) ? sc[t - o] : 0;
        __syncthreads();
        sc[t] += u;
        __syncthreads();
    }
    if (t == b) { bstart_s = sc[t] - tot; cnt_s = tot; }
    if (b == 0 && t == 255) offs[N_NODES] = sc[255];
    __syncthreads();

    int L = (t < P1_BLOCKS) ? bcnt[t * 256 + b] : 0;
    sc[t] = L;
    __syncthreads();
    for (int o = 1; o < 256; o <<= 1) {
        int u = (t >= o) ? sc[t - o] : 0;
        __syncthreads();
        sc[t] += u;
        __syncthreads();
    }
    int P = sc[t] - L;
    if (t < NPB) nhist[t] = 0;
    if (t < P1_BLOCKS && L > 0) {
        const unsigned* myrun = bpart + b * (P1_BLOCKS * SLOTP) + t * SLOTP;
        for (int i = 0; i < L; i++) ebuf[P + i] = myrun[i];
    }
    __syncthreads();

    int cnt = cnt_s;
    int n0 = b * NPB;
    for (int i = t; i < cnt; i += 256) atomicAdd(&nhist[(ebuf[i] >> 16) - n0], 1);
    __syncthreads();
    if (t < 64) {
        int v2 = (t < NPB) ? nhist[t] : 0;
        int s2 = v2;
        for (int o = 1; o < 64; o <<= 1) {
            int u = __shfl_up(s2, o, 64);
            if (t >= o) s2 += u;
        }
        if (t < NPB) {
            int ofs = bstart_s + s2 - v2;
            nhist[t] = ofs;
            offs[n0 + t] = ofs;
        }
    }
    __syncthreads();
    for (int i = t; i < cnt; i += 256) {
        unsigned pk = ebuf[i];
        int p = atomicAdd(&nhist[(pk >> 16) - n0], 1);
        csr[p] = pk & 0xFFFF;
    }
}

// -------- per-wave edge aggregate core (readlane broadcast) --------
__device__ __forceinline__ void agg_node(const __half2* __restrict__ z2,
                                         const float* __restrict__ zsi, float zdn,
                                         const int* __restrict__ csr, int o0, int deg,
                                         int lane, float& accx, float& accy, float& denom) {
    for (int base = 0; base < deg; base += 64) {
        int j = base + lane;
        int sreg = 0;
        float ex = 0.f;
        if (j < deg) {
            int s = csr[o0 + j];
            sreg = s;
            float e = zsi[s] + zdn;
            e = e > 0.f ? e : NEG_SLOPE * e;
            ex = __expf(e);
        }
        int cnt = min(64, deg - base);
        int q = 0;
        for (; q + 8 <= cnt; q += 8) {
#pragma unroll
            for (int u = 0; u < 8; u++) {
                int sq = __builtin_amdgcn_readlane(sreg, q + u);
                float exq = __uint_as_float(
                    __builtin_amdgcn_readlane(__float_as_uint(ex), q + u));
                denom += exq;
                float2 vf = __half22float2(z2[sq * 64]);
                accx = fmaf(exq, vf.x, accx);
                accy = fmaf(exq, vf.y, accy);
            }
        }
        for (; q < cnt; q++) {
            int sq = __builtin_amdgcn_readlane(sreg, q);
            float exq = __uint_as_float(
                __builtin_amdgcn_readlane(__float_as_uint(ex), q));
            denom += exq;
            float2 vf = __half22float2(z2[sq * 64]);
            accx = fmaf(exq, vf.x, accx);
            accy = fmaf(exq, vf.y, accy);
        }
    }
}

// -------- gemm0: z16 = fp16(x@W), zs, zd — dbuf W (32 KB) + prefetched A stream --------

__global__ __launch_bounds__(256) void gemm_k(const float* __restrict__ A,
                                              const float* __restrict__ W,
                                              const float* __restrict__ avs,
                                              const float* __restrict__ avd,
                                              __half* __restrict__ z16,
                                              float* __restrict__ zs,
                                              float* __restrict__ zd) {
    __shared__ float Wc[2][32 * HID];
    int t = threadIdx.x;
    float4 wreg[4];
    {
        const float4* Wg = (const float4*)W;
#pragma unroll
        for (int i = 0; i < 4; i++) wreg[i] = Wg[t + 256 * i];
    }
    int tx = t & 31;
    int ty = t >> 5;
    int row0 = blockIdx.x * 32 + ty * 4;
    float acc[4][4] = {{0.f}};
    float4 a_nxt[4];
#pragma unroll
    for (int r = 0; r < 4; r++) {
        int row = row0 + r;
        a_nxt[r] = (row < N_NODES) ? *(const float4*)&A[row * HID]
                                   : make_float4(0.f, 0.f, 0.f, 0.f);
    }
    for (int c = 0; c < 4; c++) {
        float4* dstb = (float4*)Wc[c & 1];
#pragma unroll
        for (int i = 0; i < 4; i++) dstb[t + 256 * i] = wreg[i];
        __syncthreads();
        if (c + 1 < 4) {
            const float4* Wg = (const float4*)(W + (c + 1) * 32 * HID);
#pragma unroll
            for (int i = 0; i < 4; i++) wreg[i] = Wg[t + 256 * i];
        }
        const float* Wb = Wc[c & 1];
#pragma unroll
        for (int k8 = 0; k8 < 32; k8 += 4) {
            float a_cur[4][4];
#pragma unroll
            for (int r = 0; r < 4; r++) {
                a_cur[r][0] = a_nxt[r].x; a_cur[r][1] = a_nxt[r].y;
                a_cur[r][2] = a_nxt[r].z; a_cur[r][3] = a_nxt[r].w;
            }
            int kn = c * 32 + k8 + 4;
            if (kn < HID) {
#pragma unroll
                for (int r = 0; r < 4; r++) {
                    int row = row0 + r;
                    a_nxt[r] = (row < N_NODES) ? *(const float4*)&A[row * HID + kn]
                                               : make_float4(0.f, 0.f, 0.f, 0.f);
                }
            }
#pragma unroll
            for (int kk = 0; kk < 4; kk++) {
                float4 wv = *(const float4*)&Wb[(k8 + kk) * HID + tx * 4];
#pragma unroll
                for (int r = 0; r < 4; r++) {
                    acc[r][0] = fmaf(a_cur[r][kk], wv.x, acc[r][0]);
                    acc[r][1] = fmaf(a_cur[r][kk], wv.y, acc[r][1]);
                    acc[r][2] = fmaf(a_cur[r][kk], wv.z, acc[r][2]);
                    acc[r][3] = fmaf(a_cur[r][kk], wv.w, acc[r][3]);
                }
            }
        }
    }
    float4 asv = *(const float4*)&avs[tx * 4];
    float4 adv = *(const float4*)&avd[tx * 4];
#pragma unroll
    for (int r = 0; r < 4; r++) {
        int row = row0 + r;
        if (row < N_NODES) {
            *(__half2*)&z16[row * HID + tx * 4]     = __floats2half2_rn(acc[r][0], acc[r][1]);
            *(__half2*)&z16[row * HID + tx * 4 + 2] = __floats2half2_rn(acc[r][2], acc[r][3]);
        }
        float ps = acc[r][0] * asv.x + acc[r][1] * asv.y + acc[r][2] * asv.z + acc[r][3] * asv.w;
        float pd = acc[r][0] * adv.x + acc[r][1] * adv.y + acc[r][2] * adv.z + acc[r][3] * adv.w;
#pragma unroll
        for (int o = 1; o < 32; o <<= 1) {
            ps += __shfl_xor(ps, o, 64);
            pd += __shfl_xor(pd, o, 64);
        }
        if (tx == 0 && row < N_NODES) { zs[row] = ps; zd[row] = pd; }
    }
}

// -------- fused: agg(l) -> hT in LDS -> gemm(l+1), dbuf W; W chunk0 loads fly during agg --------

__global__ __launch_bounds__(256) void fuse_k(const __half* __restrict__ z16i,
                                              const float* __restrict__ zsi,
                                              const float* __restrict__ zdi,
                                              const int* __restrict__ offs,
                                              const int* __restrict__ csr,
                                              const float* __restrict__ bprev,
                                              const float* __restrict__ W,
                                              const float* __restrict__ avs,
                                              const float* __restrict__ avd,
                                              __half* __restrict__ z16o,
                                              float* __restrict__ zso,
                                              float* __restrict__ zdo) {
    __shared__ float hT[16][HID];        // 8 KB
    __shared__ float Wc[2][32 * HID];    // 32 KB
    int t = threadIdx.x;
    int w = t >> 6, lane = t & 63;
    int n0 = blockIdx.x * 16;
    // W chunk 0 prefetch — loads in flight across the whole agg phase
    float4 wreg[4];
    {
        const float4* Wg = (const float4*)W;
#pragma unroll
        for (int i = 0; i < 4; i++) wreg[i] = Wg[t + 256 * i];
    }
    const __half2* z2 = (const __half2*)z16i + lane;

    float2 bv = *(const float2*)&bprev[2 * lane];
#pragma unroll
    for (int i = 0; i < 4; i++) {
        int ln = w * 4 + i;
        int n = n0 + ln;
        int o0 = offs[n];
        int deg = offs[n + 1] - o0;
        float zdn = zdi[n];
        float accx = 0.f, accy = 0.f, denom = 0.f;
        agg_node(z2, zsi, zdn, csr, o0, deg, lane, accx, accy, denom);
        float inv = 1.0f / denom;
        float vx = accx * inv + bv.x;
        float vy = accy * inv + bv.y;
        float2 hv;
        hv.x = vx > 0.f ? vx : 0.f;
        hv.y = vy > 0.f ? vy : 0.f;
        *(float2*)&hT[ln][2 * lane] = hv;
    }

    int tx = t & 31, ty = t >> 5;
    int r0 = ty * 2, r1 = ty * 2 + 1;
    float acc[2][4] = {{0.f}};
    for (int c = 0; c < 4; c++) {
        float4* dstb = (float4*)Wc[c & 1];
#pragma unroll
        for (int i = 0; i < 4; i++) dstb[t + 256 * i] = wreg[i];
        __syncthreads();                 // publishes Wc chunk c (and hT on c==0)
        if (c + 1 < 4) {
            const float4* Wg = (const float4*)(W + (c + 1) * 32 * HID);
#pragma unroll
            for (int i = 0; i < 4; i++) wreg[i] = Wg[t + 256 * i];
        }
        const float* Wb = Wc[c & 1];
        const float* h0 = &hT[r0][c * 32];
        const float* h1 = &hT[r1][c * 32];
#pragma unroll 8
        for (int kk = 0; kk < 32; kk++) {
            float f0 = h0[kk], f1 = h1[kk];
            float4 wv = *(const float4*)&Wb[kk * HID + tx * 4];
            acc[0][0] = fmaf(f0, wv.x, acc[0][0]);
            acc[0][1] = fmaf(f0, wv.y, acc[0][1]);
            acc[0][2] = fmaf(f0, wv.z, acc[0][2]);
            acc[0][3] = fmaf(f0, wv.w, acc[0][3]);
            acc[1][0] = fmaf(f1, wv.x, acc[1][0]);
            acc[1][1] = fmaf(f1, wv.y, acc[1][1]);
            acc[1][2] = fmaf(f1, wv.z, acc[1][2]);
            acc[1][3] = fmaf(f1, wv.w, acc[1][3]);
        }
    }
    float4 asv = *(const float4*)&avs[tx * 4];
    float4 adv = *(const float4*)&avd[tx * 4];
#pragma unroll
    for (int r = 0; r < 2; r++) {
        int row = n0 + (r ? r1 : r0);
        *(__half2*)&z16o[row * HID + tx * 4]     = __floats2half2_rn(acc[r][0], acc[r][1]);
        *(__half2*)&z16o[row * HID + tx * 4 + 2] = __floats2half2_rn(acc[r][2], acc[r][3]);
        float ps = acc[r][0] * asv.x + acc[r][1] * asv.y + acc[r][2] * asv.z + acc[r][3] * asv.w;
        float pd = acc[r][0] * adv.x + acc[r][1] * adv.y + acc[r][2] * adv.z + acc[r][3] * adv.w;
#pragma unroll
        for (int o = 1; o < 32; o <<= 1) {
            ps += __shfl_xor(ps, o, 64);
            pd += __shfl_xor(pd, o, 64);
        }
        if (tx == 0) { zso[row] = ps; zdo[row] = pd; }
    }
}

// -------- final-layer aggregate -> h3 --------

__global__ __launch_bounds__(256) void agg_k(const __half* __restrict__ z16,
                                             const float* __restrict__ zs,
                                             const float* __restrict__ zd,
                                             const int* __restrict__ offs,
                                             const int* __restrict__ csr,
                                             const float* __restrict__ b,
                                             float* __restrict__ hout) {
    int t = threadIdx.x;
    int w = t >> 6, lane = t & 63;
    int n = blockIdx.x * 4 + w;
    if (n >= N_NODES) return;
    int o0 = offs[n];
    int deg = offs[n + 1] - o0;
    float zdn = zd[n];
    const __half2* z2 = (const __half2*)z16 + lane;
    float accx = 0.f, accy = 0.f, denom = 0.f;
    agg_node(z2, zs, zdn, csr, o0, deg, lane, accx, accy, denom);
    float inv = 1.0f / denom;
    float2 bv = *(const float2*)&b[2 * lane];
    float vx = accx * inv + bv.x;
    float vy = accy * inv + bv.y;
    float2 o;
    o.x = vx > 0.f ? vx : 0.f;
    o.y = vy > 0.f ? vy : 0.f;
    *(float2*)&hout[n * HID + 2 * lane] = o;
}

// -------- action scoring: tiled GEMM, 16 actions/block × 256 blocks, dbuf W1 --------

#define SC_APB 16

__global__ __launch_bounds__(256) void score_k(const float* __restrict__ h,
                                               const int* __restrict__ asrc,
                                               const int* __restrict__ adst,
                                               const int* __restrict__ atype,
                                               const float* __restrict__ W1,
                                               const float* __restrict__ b1,
                                               const float* __restrict__ W2,
                                               const float* __restrict__ b2,
                                               float* __restrict__ out) {
    __shared__ float featT[257][SC_APB + 1];   // [k][action], padded: 17.5 KB
    __shared__ float Wc[2][32 * HID];          // 32 KB
    int t = threadIdx.x;
    int a0 = blockIdx.x * SC_APB;

    float4 wreg[4];
    {
        const float4* Wg = (const float4*)W1;
#pragma unroll
        for (int i = 0; i < 4; i++) wreg[i] = Wg[t + 256 * i];
    }
    // gather feat (transposed): coalesced h-row reads, conflict-free LDS writes
    for (int idx = t; idx < SC_APB * 128; idx += 256) {
        int a = idx >> 7, c = idx & 127;
        featT[c][a]       = h[asrc[a0 + a] * HID + c];
        featT[128 + c][a] = h[adst[a0 + a] * HID + c];
    }
    if (t < SC_APB) featT[256][t] = (float)atype[a0 + t];

    int cg = t & 31, ap = t >> 5;              // 4 cols (cg*4), actions ap*2, ap*2+1
    float4 bv = *(const float4*)&b1[cg * 4];
    float acc0[4] = {bv.x, bv.y, bv.z, bv.w};
    float acc1[4] = {bv.x, bv.y, bv.z, bv.w};

    for (int c = 0; c < 8; c++) {
        float4* dstb = (float4*)Wc[c & 1];
#pragma unroll
        for (int i = 0; i < 4; i++) dstb[t + 256 * i] = wreg[i];
        __syncthreads();                       // publishes chunk c (and featT on c==0)
        if (c + 1 < 8) {
            const float4* Wg = (const float4*)(W1 + (c + 1) * 32 * HID);
#pragma unroll
            for (int i = 0; i < 4; i++) wreg[i] = Wg[t + 256 * i];
        }
        const float* Wb = Wc[c & 1];
        const float* fT = &featT[c * 32][0];
#pragma unroll 8
        for (int kk = 0; kk < 32; kk++) {
            float4 wv = *(const float4*)&Wb[kk * HID + cg * 4];
            float f0 = fT[kk * (SC_APB + 1) + ap * 2];
            float f1 = fT[kk * (SC_APB + 1) + ap * 2 + 1];
            acc0[0] = fmaf(f0, wv.x, acc0[0]);
            acc0[1] = fmaf(f0, wv.y, acc0[1]);
            acc0[2] = fmaf(f0, wv.z, acc0[2]);
            acc0[3] = fmaf(f0, wv.w, acc0[3]);
            acc1[0] = fmaf(f1, wv.x, acc1[0]);
            acc1[1] = fmaf(f1, wv.y, acc1[1]);
            acc1[2] = fmaf(f1, wv.z, acc1[2]);
            acc1[3] = fmaf(f1, wv.w, acc1[3]);
        }
    }
    // k = 256 (type flag row)
    {
        float4 wv = *(const float4*)&W1[256 * HID + cg * 4];
        float f0 = featT[256][ap * 2];
        float f1 = featT[256][ap * 2 + 1];
        acc0[0] = fmaf(f0, wv.x, acc0[0]); acc0[1] = fmaf(f0, wv.y, acc0[1]);
        acc0[2] = fmaf(f0, wv.z, acc0[2]); acc0[3] = fmaf(f0, wv.w, acc0[3]);
        acc1[0] = fmaf(f1, wv.x, acc1[0]); acc1[1] = fmaf(f1, wv.y, acc1[1]);
        acc1[2] = fmaf(f1, wv.z, acc1[2]); acc1[3] = fmaf(f1, wv.w, acc1[3]);
    }
    float4 w2v = *(const float4*)&W2[cg * 4];
    float v0 = 0.f, v1 = 0.f;
    v0 += (acc0[0] > 0.f ? acc0[0] : 0.f) * w2v.x;
    v0 += (acc0[1] > 0.f ? acc0[1] : 0.f) * w2v.y;
    v0 += (acc0[2] > 0.f ? acc0[2] : 0.f) * w2v.z;
    v0 += (acc0[3] > 0.f ? acc0[3] : 0.f) * w2v.w;
    v1 += (acc1[0] > 0.f ? acc1[0] : 0.f) * w2v.x;
    v1 += (acc1[1] > 0.f ? acc1[1] : 0.f) * w2v.y;
    v1 += (acc1[2] > 0.f ? acc1[2] : 0.f) * w2v.z;
    v1 += (acc1[3] > 0.f ? acc1[3] : 0.f) * w2v.w;
#pragma unroll
    for (int o = 1; o < 32; o <<= 1) {
        v0 += __shfl_xor(v0, o, 64);
        v1 += __shfl_xor(v1, o, 64);
    }
    if (cg == 0) {
        out[a0 + ap * 2]     = v0 + b2[0];
        out[a0 + ap * 2 + 1] = v1 + b2[0];
    }
}

// ---------------- launch ----------------

extern "C" void kernel_launch(void* const* d_in, const int* in_sizes, int n_in,
                              void* d_out, int out_size, void* d_ws, size_t ws_size,
                              hipStream_t stream) {
    const float* x   = (const float*)d_in[0];
    const int* ei    = (const int*)d_in[1];
    const int* asrc  = (const int*)d_in[2];
    const int* adst  = (const int*)d_in[3];
    const int* atype = (const int*)d_in[4];
    const float* gW  = (const float*)d_in[5];
    const float* gas = (const float*)d_in[6];
    const float* gad = (const float*)d_in[7];
    const float* gb  = (const float*)d_in[8];
    const float* W1  = (const float*)d_in[9];
    const float* b1  = (const float*)d_in[10];
    const float* W2  = (const float*)d_in[11];
    const float* b2  = (const float*)d_in[12];
    float* out = (float*)d_out;

    __half* z16A = (__half*)d_ws;                       // 2.56 MB
    __half* z16B = z16A + N_NODES * HID;                // 2.56 MB
    float* h3   = (float*)(z16B + N_NODES * HID);       // 5.12 MB
    float* zsA  = h3 + N_NODES * HID;
    float* zdA  = zsA + N_NODES;
    float* zsB  = zdA + N_NODES;
    float* zdB  = zsB + N_NODES;
    int* offs   = (int*)(zdB + N_NODES);
    int* csr    = offs + (N_NODES + 1);
    int* bcnt   = csr + TOT_E;
    unsigned* bpart = (unsigned*)(bcnt + P1_BLOCKS * 256);

    part1_k<<<P1_BLOCKS, 256, 0, stream>>>(ei, bpart, bcnt);
    part2_k<<<NBKT, 256, 0, stream>>>(bpart, bcnt, csr, offs);

    gemm_k<<<(N_NODES + 31) / 32, 256, 0, stream>>>(x, gW, gas, gad, z16A, zsA, zdA);
    fuse_k<<<N_NODES / 16, 256, 0, stream>>>(z16A, zsA, zdA, offs, csr, gb,
                                             gW + 1 * HID * HID, gas + 1 * HID, gad + 1 * HID,
                                             z16B, zsB, zdB);
    fuse_k<<<N_NODES / 16, 256, 0, stream>>>(z16B, zsB, zdB, offs, csr, gb + 1 * HID,
                                             gW + 2 * HID * HID, gas + 2 * HID, gad + 2 * HID,
                                             z16A, zsA, zdA);
    agg_k<<<(N_NODES + 3) / 4, 256, 0, stream>>>(z16A, zsA, zdA, offs, csr,
                                                 gb + 2 * HID, h3);
    score_k<<<N_ACT / SC_APB, 256, 0, stream>>>(h3, asrc, adst, atype,
                                                W1, b1, W2, b2, out);
}